// Round 7
// baseline (305.330 us; speedup 1.0000x reference)
//
#include <hip/hip_runtime.h>

typedef float f2 __attribute__((ext_vector_type(2)));
typedef float f4 __attribute__((ext_vector_type(4)));
typedef _Float16 h2 __attribute__((ext_vector_type(2)));
typedef _Float16 h4 __attribute__((ext_vector_type(4)));

#define IN_H 128
#define IN_W 128
#define NCH  128
#define UPN  256

constexpr int SEG  = 8;    // output rows per block
constexpr int COLS = 32;   // output cols per block
constexpr int CH   = 32;   // channels per block
constexpr int IRW  = 14;   // input row window  (i0-3 .. i0+10)
constexpr int ICW  = 38;   // input col window  (jc0-3 .. jc0+34)
constexpr int NT4  = IRW * ICW * CH / 4;   // 4256 f4 staging tasks
constexpr int TPR  = ICW * CH / 4;         // 304 tasks per input row

__device__ __forceinline__ float cubic_k(float x) {
  // Keys cubic, a = -0.5, x >= 0
  float r = 0.f;
  if (x < 1.f)      r = (1.5f * x - 2.5f) * x * x + 1.f;
  else if (x < 2.f) r = ((-0.5f * x + 2.5f) * x - 4.f) * x + 2.f;
  return r;
}

__device__ __forceinline__ h4 pk4(f4 v) {
  h2 lo = __builtin_bit_cast(h2, __builtin_amdgcn_cvt_pkrtz(v.x, v.y));
  h2 hi = __builtin_bit_cast(h2, __builtin_amdgcn_cvt_pkrtz(v.z, v.w));
  h4 r; r.x = lo.x; r.y = lo.y; r.z = hi.x; r.w = hi.y;
  return r;
}

__global__ __launch_bounds__(256, 3)
void actfilter_kernel(const float* __restrict__ x, float* __restrict__ out) {
  // f16 storage: col stride = 32 halves = 16 dwords -> adjacent cols are 16
  // banks apart -> exact 2-way (free) on the h2 reads.
  __shared__ __align__(16) _Float16 xin[IRW][ICW][CH];   // 34048 B
  __shared__ __align__(16) float upw[UPN][4];            //  4096 B
  __shared__ __align__(16) float dww[IN_H][8];           //  4096 B

  const int tid = threadIdx.x;

  // XCD swizzle: batch image -> XCD; ch-chunks + neighbor tiles adjacent.
  int bid  = blockIdx.x;
  int work = ((bid & 7) << 8) | (bid >> 3);
  const int b   = work >> 8;
  const int rs  = (work >> 4) & 15;
  const int cs  = (work >> 2) & 3;
  const int chs = work & 3;
  const int i0  = rs * SEG;
  const int jc0 = cs * COLS;
  const int c0  = chs * CH;
  const int mlo = i0 - 3;

  const float* xbase = x   + (size_t)b * IN_H * IN_W * NCH;
  float*       obase = out + (size_t)b * IN_H * IN_W * NCH;

  // ---- staging: global f32 -> f16 LDS, small reg batches (no spills) ----
  auto ldb = [&](int base, int cnt, f4* v) {
#pragma unroll
    for (int k = 0; k < 6; ++k) {
      if (k < cnt) {
        int t = tid + (base + k) * 256;
        if (t < NT4) {
          int row   = t / TPR;
          int rem   = t - row * TPR;
          int col   = rem >> 3;
          int piece = rem & 7;
          int gr = min(max(mlo + row, 0), IN_H - 1);
          int gc = min(max(jc0 - 3 + col, 0), IN_W - 1);
          v[k] = *(const f4*)(xbase + ((size_t)gr * IN_W + gc) * NCH
                              + c0 + piece * 4);
        }
      }
    }
  };
  auto stb = [&](int base, int cnt, const f4* v) {
#pragma unroll
    for (int k = 0; k < 6; ++k) {
      if (k < cnt) {
        int t = tid + (base + k) * 256;
        if (t < NT4) {
          int row   = t / TPR;
          int rem   = t - row * TPR;
          int col   = rem >> 3;
          int piece = rem & 7;
          *(h4*)&xin[row][col][piece * 4] = pk4(v[k]);
        }
      }
    }
  };

  f4 sA[6], sB[6];
  ldb(0, 6, sA);       // batch 0 in flight; table build covers latency

  // ---- upsample weight table ----
  {
    int o = tid;                     // 0..255 upsample positions
    int k = o >> 1;
    int base = (o & 1) ? (k - 1) : (k - 2);
    float s = 0.5f * o - 0.25f;
    float w[4]; float sum = 0.f;
#pragma unroll
    for (int t = 0; t < 4; ++t) {
      int tap = base + t;
      float wt = (tap >= 0 && tap < IN_H) ? cubic_k(fabsf(s - (float)tap)) : 0.f;
      w[t] = wt; sum += wt;
    }
    float inv = 1.f / sum;
#pragma unroll
    for (int t = 0; t < 4; ++t) upw[o][t] = w[t] * inv;
  }

  ldb(6, 6, sB);
  stb(0, 6, sA);

  // ---- downsample weight table ----
  if (tid < IN_H) {
    int j = tid;                     // 0..127 downsample positions
    float s = 2.f * j + 0.5f;
    float w[8]; float sum = 0.f;
#pragma unroll
    for (int t = 0; t < 8; ++t) {
      int tap = 2 * j - 3 + t;
      float wt = (tap >= 0 && tap < UPN) ? cubic_k(0.5f * fabsf(s - (float)tap)) : 0.f;
      w[t] = wt; sum += wt;
    }
    float inv = 1.f / sum;
#pragma unroll
    for (int t = 0; t < 8; ++t) dww[j][t] = w[t] * inv;
  }

  ldb(12, 5, sA);
  stb(6, 6, sB);
  stb(12, 5, sA);

  __syncthreads();   // the ONLY barrier: xin (f16) + tables ready

  // ---- per-thread mapping: col-pair cp (0..15), ch-pair e (0..15) ----
  const int cp = tid >> 4;
  const int e  = tid & 15;
  const int j0 = jc0 + 2 * cp;       // output cols j0, j0+1

  f4 wvv[10];                        // W-upsample weights (edge renorm baked)
#pragma unroll
  for (int c = 0; c < 10; ++c) {
    int cu = min(max(2 * j0 - 3 + c, 0), UPN - 1);
    wvv[c] = *(const f4*)&upw[cu][0];
  }
  float dw0[8], dw1[8];              // W-downsample weights, cols j0 / j0+1
#pragma unroll
  for (int t = 0; t < 8; ++t) { dw0[t] = dww[j0][t]; dw1[t] = dww[j0 + 1][t]; }

  const int r_lo = max(2 * i0 - 3, 0);
  const int r_hi = min(2 * i0 + 2 * SEG + 2, UPN - 1);

  // Interior H-up weights are exact dyadic constants, chosen statically by
  // r parity; only r<3 / r>252 (rs 0/15 blocks) fall back to the table.
  const f4 whE = {-0.0234375f, 0.2265625f, 0.8671875f, -0.0703125f};
  const f4 whO = {-0.0703125f, 0.8671875f, 0.2265625f, -0.0234375f};

  f2 tw[4][10];                      // W-upsampled row ring (static-indexed)
  f2 accA[4], accB[4];               // H-down accumulators (f32)
#pragma unroll
  for (int s2 = 0; s2 < 4; ++s2) {
    accA[s2] = (f2){0.f, 0.f};
    accB[s2] = (f2){0.f, 0.f};
  }

#define DO_R(RV, WHC, S0, S1, S2, S3)                                        \
  do {                                                                       \
    int r = (RV);                                                            \
    if (r >= r_lo && r <= r_hi) {                                            \
      f4 wh = (WHC);                                                         \
      if (r < 3 || r > 252) wh = *(const f4*)&upw[r][0];                     \
      f2 z0 = (f2){0.f, 0.f}, z1 = (f2){0.f, 0.f};                           \
      _Pragma("unroll")                                                      \
      for (int c = 0; c < 10; ++c) {                                         \
        f2 hu = wh.x * tw[S0][c] + wh.y * tw[S1][c]                          \
              + wh.z * tw[S2][c] + wh.w * tw[S3][c];                         \
        f2 lv;                                                               \
        lv.x = fmaxf(hu.x, 0.01f * hu.x);                                    \
        lv.y = fmaxf(hu.y, 0.01f * hu.y);                                    \
        if (c < 8)  z0 += dw0[c] * lv;                                       \
        if (c >= 2) z1 += dw1[c - 2] * lv;                                   \
      }                                                                      \
      int ilo = max(i0, (r - 3) >> 1);                                       \
      int ihi = min(i0 + SEG - 1, (r + 3) >> 1);                             \
      _Pragma("unroll")                                                      \
      for (int s = 0; s < 4; ++s) {                                          \
        int i = ilo + ((s - ilo) & 3);                                       \
        if (i <= ihi) {                                                      \
          float w = dww[i][r - 2 * i + 3];                                   \
          accA[s] += w * z0;                                                 \
          accB[s] += w * z1;                                                 \
          bool done = (r == 2 * i + 4) ||                                    \
                      (r == UPN - 1 && 2 * i + 4 > UPN - 1);                 \
          if (done) {                                                        \
            float* dst = obase + ((size_t)i * IN_W + j0) * NCH + c0 + 2 * e; \
            *(f2*)dst         = accA[s];                                     \
            *(f2*)(dst + NCH) = accB[s];                                     \
            accA[s] = (f2){0.f, 0.f};                                        \
            accB[s] = (f2){0.f, 0.f};                                        \
          }                                                                  \
        }                                                                    \
      }                                                                      \
    }                                                                        \
  } while (0)

// ST is a compile-time literal 0..13: LDS row offset and ring slots static.
#define STEP(ST)                                                             \
  do {                                                                       \
    int m = mlo + (ST);                                                      \
    f2 rawf[8];                                                              \
    _Pragma("unroll")                                                        \
    for (int k = 0; k < 8; ++k) {                                            \
      h2 rv = *(const h2*)&xin[(ST)][2 * cp + k][2 * e];                     \
      rawf[k].x = (float)rv.x;                                               \
      rawf[k].y = (float)rv.y;                                               \
    }                                                                        \
    _Pragma("unroll")                                                        \
    for (int c = 0; c < 10; ++c) {                                           \
      tw[(ST) & 3][c] = wvv[c].x * rawf[(c >> 1) + 0]                        \
                      + wvv[c].y * rawf[(c >> 1) + 1]                        \
                      + wvv[c].z * rawf[(c >> 1) + 2]                        \
                      + wvv[c].w * rawf[(c >> 1) + 3];                       \
    }                                                                        \
    DO_R(2 * m - 3, whO, ((ST) + 1) & 3, ((ST) + 2) & 3, ((ST) + 3) & 3, (ST) & 3); \
    DO_R(2 * m - 2, whE, ((ST) + 1) & 3, ((ST) + 2) & 3, ((ST) + 3) & 3, (ST) & 3); \
  } while (0)

  STEP(0);  STEP(1);  STEP(2);  STEP(3);
  STEP(4);  STEP(5);  STEP(6);  STEP(7);
  STEP(8);  STEP(9);  STEP(10); STEP(11);
  STEP(12); STEP(13);

#undef STEP
#undef DO_R
}

extern "C" void kernel_launch(void* const* d_in, const int* in_sizes, int n_in,
                              void* d_out, int out_size, void* d_ws, size_t ws_size,
                              hipStream_t stream) {
  const float* x = (const float*)d_in[0];
  float* out = (float*)d_out;
  actfilter_kernel<<<dim3(2048), dim3(256), 0, stream>>>(x, out);
}

// Round 8
// 76.335 us; speedup vs baseline: 3.9999x; 3.9999x over previous
//
#include <hip/hip_runtime.h>

typedef float f2 __attribute__((ext_vector_type(2)));
typedef float f4 __attribute__((ext_vector_type(4)));

#define IN_H 128
#define IN_W 128
#define NCH  128
#define UPN  256

constexpr int SEG  = 8;    // output rows per block
constexpr int COLS = 32;   // output cols per block
constexpr int CH   = 32;   // channels per block
constexpr int IRW  = 14;   // input row window  (i0-3 .. i0+10)
constexpr int ICW  = 38;   // input col window  (jc0-3 .. jc0+34)
constexpr int NT4  = IRW * ICW * CH / 4;   // 4256 16-byte staging tasks

__device__ __forceinline__ float cubic_k(float x) {
  // Keys cubic, a = -0.5, x >= 0
  float r = 0.f;
  if (x < 1.f)      r = (1.5f * x - 2.5f) * x * x + 1.f;
  else if (x < 2.f) r = ((-0.5f * x + 2.5f) * x - 4.f) * x + 2.f;
  return r;
}

// global -> LDS direct copy, 16 B per lane (LDS dest wave-uniform base).
#define GLDS(g, l)                                                         \
  __builtin_amdgcn_global_load_lds(                                        \
      (const __attribute__((address_space(1))) void*)(g),                  \
      (__attribute__((address_space(3))) void*)(l), 16, 0, 0)

__global__ __launch_bounds__(256, 2)
void actfilter_kernel(const float* __restrict__ x, float* __restrict__ out) {
  __shared__ __align__(16) float xin[IRW][ICW][CH];  // 68096 B
  __shared__ __align__(16) float upw[UPN][4];        //  4096 B
  __shared__ __align__(16) float dww[IN_H][8];       //  4096 B

  const int tid = threadIdx.x;

  // XCD swizzle: batch image -> XCD; ch-chunks + neighbor tiles adjacent.
  int bid  = blockIdx.x;
  int work = ((bid & 7) << 8) | (bid >> 3);
  const int b   = work >> 8;
  const int rs  = (work >> 4) & 15;
  const int cs  = (work >> 2) & 3;
  const int chs = work & 3;
  const int i0  = rs * SEG;
  const int jc0 = cs * COLS;
  const int c0  = chs * CH;
  const int mlo = i0 - 3;
  const int mhi = i0 + 10;

  const float* xbase = x   + (size_t)b * IN_H * IN_W * NCH;
  float*       obase = out + (size_t)b * IN_H * IN_W * NCH;

  // ---- issue ALL staging loads first (latency hides under table build) ----
  {
    char* lbase = (char*)&xin[0][0][0] + ((tid >> 6) << 10);
#pragma unroll
    for (int pass = 0; pass < 17; ++pass) {
      int t = tid + pass * 256;
      if (t < NT4) {
        int row   = t / 304;            // 304 = ICW*CH/4 tasks per input row
        int rem   = t - row * 304;
        int col   = rem >> 3;
        int piece = rem & 7;
        int gr = min(max(mlo + row, 0), IN_H - 1);
        int gc = min(max(jc0 - 3 + col, 0), IN_W - 1);
        const float* gp = xbase + ((size_t)gr * IN_W + gc) * NCH + c0 + piece * 4;
        GLDS(gp, lbase + pass * 4096);
      }
    }
  }

  // ---- weight tables (VALU work overlapping the loads) ----
  {
    int o = tid;                       // 0..255 upsample positions
    int k = o >> 1;
    int base = (o & 1) ? (k - 1) : (k - 2);
    float s = 0.5f * o - 0.25f;
    float w[4]; float sum = 0.f;
#pragma unroll
    for (int t = 0; t < 4; ++t) {
      int tap = base + t;
      float wt = (tap >= 0 && tap < IN_H) ? cubic_k(fabsf(s - (float)tap)) : 0.f;
      w[t] = wt; sum += wt;
    }
    float inv = 1.f / sum;
#pragma unroll
    for (int t = 0; t < 4; ++t) upw[o][t] = w[t] * inv;
  }
  if (tid < IN_H) {
    int j = tid;                       // 0..127 downsample positions
    float s = 2.f * j + 0.5f;
    float w[8]; float sum = 0.f;
#pragma unroll
    for (int t = 0; t < 8; ++t) {
      int tap = 2 * j - 3 + t;
      float wt = (tap >= 0 && tap < UPN) ? cubic_k(0.5f * fabsf(s - (float)tap)) : 0.f;
      w[t] = wt; sum += wt;
    }
    float inv = 1.f / sum;
#pragma unroll
    for (int t = 0; t < 8; ++t) dww[j][t] = w[t] * inv;
  }

  __syncthreads();   // the ONLY barrier: xin + tables ready

  // ---- per-thread mapping: col-pair cp (0..15), ch-pair e (0..15) ----
  const int cp = tid >> 4;
  const int e  = tid & 15;
  const int j0 = jc0 + 2 * cp;         // output cols j0, j0+1

  // W-upsample weights for this thread's 10 u-cols (edge renorm baked in)
  f4 wvv[10];
#pragma unroll
  for (int c = 0; c < 10; ++c) {
    int cu = min(max(2 * j0 - 3 + c, 0), UPN - 1);
    wvv[c] = *(const f4*)&upw[cu][0];
  }
  // W-downsample weights for cols j0, j0+1
  float dw0[8], dw1[8];
  {
    f4 a = *(const f4*)&dww[j0][0],     bq = *(const f4*)&dww[j0][4];
    f4 c2 = *(const f4*)&dww[j0 + 1][0], d = *(const f4*)&dww[j0 + 1][4];
#pragma unroll
    for (int t = 0; t < 4; ++t) {
      dw0[t] = a[t]; dw0[t + 4] = bq[t];
      dw1[t] = c2[t]; dw1[t + 4] = d[t];
    }
  }

  const int r_lo = max(2 * i0 - 3, 0);
  const int r_hi = min(2 * i0 + 2 * SEG + 2, UPN - 1);

  // Interior 2x-bicubic H-up weights are exact dyadic constants (sum = 1);
  // selected statically by r parity. Only r<3 / r>252 (rs 0/15 blocks) need
  // the renormalized table -> wave-uniform fallback branch.
  const f4 whE = {-0.0234375f, 0.2265625f, 0.8671875f, -0.0703125f};
  const f4 whO = {-0.0703125f, 0.8671875f, 0.2265625f, -0.0234375f};

  f2 tw[4][10];                        // W-upsampled row ring (static-indexed)
  f2 accA[4], accB[4];
#pragma unroll
  for (int s2 = 0; s2 < 4; ++s2) {
    accA[s2] = (f2){0.f, 0.f};
    accB[s2] = (f2){0.f, 0.f};
  }

#define DO_R(RV, WHC, S0, S1, S2, S3)                                        \
  do {                                                                       \
    int r = (RV);                                                            \
    if (r >= r_lo && r <= r_hi) {                                            \
      f4 wh = (WHC);                                                         \
      if (r < 3 || r > 252) wh = *(const f4*)&upw[r][0];                     \
      f2 z0 = (f2){0.f, 0.f}, z1 = (f2){0.f, 0.f};                           \
      _Pragma("unroll")                                                      \
      for (int c = 0; c < 10; ++c) {                                         \
        f2 hu = wh.x * tw[S0][c] + wh.y * tw[S1][c]                          \
              + wh.z * tw[S2][c] + wh.w * tw[S3][c];                         \
        f2 lv;                                                               \
        lv.x = fmaxf(hu.x, 0.01f * hu.x);                                    \
        lv.y = fmaxf(hu.y, 0.01f * hu.y);                                    \
        if (c < 8)  z0 += dw0[c] * lv;                                       \
        if (c >= 2) z1 += dw1[c - 2] * lv;                                   \
      }                                                                      \
      int ilo = max(i0, (r - 3) >> 1);                                       \
      int ihi = min(i0 + SEG - 1, (r + 3) >> 1);                             \
      _Pragma("unroll")                                                      \
      for (int s = 0; s < 4; ++s) {                                          \
        int i = ilo + ((s - ilo) & 3);                                       \
        if (i <= ihi) {                                                      \
          float w = dww[i][r - 2 * i + 3];                                   \
          accA[s] += w * z0;                                                 \
          accB[s] += w * z1;                                                 \
          bool done = (r == 2 * i + 4) ||                                    \
                      (r == UPN - 1 && 2 * i + 4 > UPN - 1);                 \
          if (done) {                                                        \
            float* dst = obase + ((size_t)i * IN_W + j0) * NCH + c0 + 2 * e; \
            *(f2*)dst         = accA[s];                                     \
            *(f2*)(dst + NCH) = accB[s];                                     \
            accA[s] = (f2){0.f, 0.f};                                        \
            accB[s] = (f2){0.f, 0.f};                                        \
          }                                                                  \
        }                                                                    \
      }                                                                      \
    }                                                                        \
  } while (0)

#define STEP(PH)                                                             \
  do {                                                                       \
    int m = mlo + mb + (PH);                                                 \
    if (m <= mhi) {                                                          \
      int ml = m - mlo;                                                      \
      f2 raw[8];                                                             \
      _Pragma("unroll")                                                      \
      for (int k = 0; k < 8; ++k)                                            \
        raw[k] = *(const f2*)&xin[ml][2 * cp + k][2 * e];                    \
      _Pragma("unroll")                                                      \
      for (int c = 0; c < 10; ++c) {                                         \
        tw[(PH) & 3][c] = wvv[c].x * raw[(c >> 1) + 0]                       \
                        + wvv[c].y * raw[(c >> 1) + 1]                       \
                        + wvv[c].z * raw[(c >> 1) + 2]                       \
                        + wvv[c].w * raw[(c >> 1) + 3];                      \
      }                                                                      \
      DO_R(2 * m - 3, whO, ((PH) + 1) & 3, ((PH) + 2) & 3, ((PH) + 3) & 3, (PH) & 3); \
      DO_R(2 * m - 2, whE, ((PH) + 1) & 3, ((PH) + 2) & 3, ((PH) + 3) & 3, (PH) & 3); \
    }                                                                        \
  } while (0)

  // 14 m-steps, unrolled in groups of 4 so ring slots are compile-time.
  for (int mb = 0; mb < 16; mb += 4) {
    STEP(0);
    STEP(1);
    STEP(2);
    STEP(3);
  }

#undef STEP
#undef DO_R
}

extern "C" void kernel_launch(void* const* d_in, const int* in_sizes, int n_in,
                              void* d_out, int out_size, void* d_ws, size_t ws_size,
                              hipStream_t stream) {
  const float* x = (const float*)d_in[0];
  float* out = (float*)d_out;
  actfilter_kernel<<<dim3(2048), dim3(256), 0, stream>>>(x, out);
}